// Round 6
// baseline (226.444 us; speedup 1.0000x reference)
//
#include <hip/hip_runtime.h>
#include <hip/hip_bf16.h>
#include <math.h>

typedef __attribute__((ext_vector_type(8))) short short8;
typedef __attribute__((ext_vector_type(4))) float f32x4;
typedef __attribute__((ext_vector_type(2))) float f32x2;

__device__ __forceinline__ float bf2f(unsigned short u) {
  union { unsigned int i; float f; } x; x.i = ((unsigned int)u) << 16; return x.f;
}

__device__ __forceinline__ void load_lds16(const void* g, void* l) {
  __builtin_amdgcn_global_load_lds(
      (const __attribute__((address_space(1))) unsigned int*)g,
      (__attribute__((address_space(3))) unsigned int*)l, 16, 0, 0);
}

// ---------------- bf16 MFMA GEMM, bf16 output ----------------
__global__ __launch_bounds__(256) void gemm_mfma(
    const __hip_bfloat16* __restrict__ A, const __hip_bfloat16* __restrict__ B,
    const float* __restrict__ bl, const float* __restrict__ br, int halfN,
    __hip_bfloat16* __restrict__ out, int M, int K, int Nout) {
  __shared__ __hip_bfloat16 As[128 * 32];
  __shared__ __hip_bfloat16 Bs[128 * 32];
  int t = threadIdx.x;
  int w = t >> 6, l = t & 63;
  int lr = l & 15, lh = l >> 4;
  int wr = w >> 1, wc = w & 1;
  int m0 = blockIdx.y * 128, n0 = blockIdx.x * 128;
  f32x4 acc[4][4] = {};
  int nk = K >> 5;
  for (int ks = 0; ks < nk; ++ks) {
    int k0 = ks << 5;
#pragma unroll
    for (int p = 0; p < 2; ++p) {
      int c = p * 256 + t;
      int row = c >> 2, sub = c & 3;
      int gm = m0 + row; if (gm >= M) gm = M - 1;
      const __hip_bfloat16* gsrc = A + (size_t)gm * K + k0 + sub * 8;
      char* ldst = (char*)As + (size_t)(p * 256 + w * 64) * 16;
      load_lds16(gsrc, ldst);
    }
#pragma unroll
    for (int p = 0; p < 2; ++p) {
      int c = p * 256 + t;
      int row = c >> 2, sub = c & 3;
      const __hip_bfloat16* gsrc = B + (size_t)(n0 + row) * K + k0 + sub * 8;
      char* ldst = (char*)Bs + (size_t)(p * 256 + w * 64) * 16;
      load_lds16(gsrc, ldst);
    }
    __syncthreads();
    short8 af[4], bf[4];
#pragma unroll
    for (int mt = 0; mt < 4; ++mt)
      af[mt] = *(const short8*)(As + (size_t)(wr * 64 + mt * 16 + lr) * 32 + lh * 8);
#pragma unroll
    for (int nt = 0; nt < 4; ++nt)
      bf[nt] = *(const short8*)(Bs + (size_t)(wc * 64 + nt * 16 + lr) * 32 + lh * 8);
#pragma unroll
    for (int mt = 0; mt < 4; ++mt)
#pragma unroll
      for (int nt = 0; nt < 4; ++nt)
        acc[mt][nt] = __builtin_amdgcn_mfma_f32_16x16x32_bf16(af[mt], bf[nt], acc[mt][nt], 0, 0, 0);
    __syncthreads();
  }
#pragma unroll
  for (int mt = 0; mt < 4; ++mt) {
#pragma unroll
    for (int r = 0; r < 4; ++r) {
      int gm = m0 + wr * 64 + mt * 16 + lh * 4 + r;
      if (gm >= M) continue;
#pragma unroll
      for (int nt = 0; nt < 4; ++nt) {
        int gn = n0 + wc * 64 + nt * 16 + lr;
        float bv = (gn < halfN) ? bl[gn] : br[gn - halfN];
        out[(size_t)gm * Nout + gn] = __float2bfloat16(acc[mt][nt][r] + bv);
      }
    }
  }
}

// ---------------- fused cast (all weights + x) ----------------
struct CastSeg { const float* src; __hip_bfloat16* dst; int rows, K, Kp, row0, start; };
struct CastArgs { CastSeg s[7]; int total; };

__global__ __launch_bounds__(256) void k_cast_all(CastArgs A) {
  int stride = gridDim.x * blockDim.x;
  for (int i = blockIdx.x * blockDim.x + threadIdx.x; i < A.total; i += stride) {
    int si = 0;
#pragma unroll
    for (int j = 1; j < 7; j++) if (i >= A.s[j].start) si = j;
    CastSeg sg = A.s[si];
    int li = i - sg.start;
    int r = li / sg.Kp, k = li - r * sg.Kp;
    float v = (k < sg.K) ? sg.src[(size_t)r * sg.K + k] : 0.f;
    sg.dst[(size_t)(sg.row0 + r) * sg.Kp + k] = __float2bfloat16(v);
  }
}

// ---------------- CSR construction ----------------
__global__ void k_hist(const int* __restrict__ ei, int E, int N, int* __restrict__ deg) {
  int e = blockIdx.x * blockDim.x + threadIdx.x;
  int ET = E + N;
  if (e >= ET) return;
  int d = (e < E) ? ei[E + e] : (e - E);
  atomicAdd(&deg[d], 1);
}

__global__ __launch_bounds__(256) void k_scan_one(const int* __restrict__ deg, int N,
                                                  int* __restrict__ rp, int* __restrict__ cursor) {
  __shared__ int part[256];
  int t = threadIdx.x;
  int chunk = (N + 255) / 256;
  int lo = t * chunk;
  int hi = lo + chunk; if (hi > N) hi = N;
  int s = 0;
  for (int i = lo; i < hi; ++i) s += deg[i];
  part[t] = s;
  __syncthreads();
  for (int off = 1; off < 256; off <<= 1) {
    int x = (t >= off) ? part[t - off] : 0;
    __syncthreads();
    part[t] += x;
    __syncthreads();
  }
  int run = (t == 0) ? 0 : part[t - 1];
  for (int i = lo; i < hi; ++i) {
    rp[i] = run;
    cursor[i] = run;
    run += deg[i];
  }
  if (t == 255) rp[N] = run;
}

__global__ void k_scatter(const int* __restrict__ ei, int E, int N,
                          int* __restrict__ cursor, int* __restrict__ srcs) {
  int e = blockIdx.x * blockDim.x + threadIdx.x;
  int ET = E + N;
  if (e >= ET) return;
  int s = (e < E) ? ei[e] : (e - E);
  int d = (e < E) ? ei[E + e] : (e - E);
  int pos = atomicAdd(&cursor[d], 1);
  srcs[pos] = s;
}

// ---------------- fused edge phase: 2 waves per node + LDS combine ----------------
template <int CPL> struct VecSel;
template <> struct VecSel<8> { using T = short8; };
template <> struct VecSel<2> { using T = unsigned int; };

// 512 threads = 8 waves = 4 nodes x 2 half-segments. Each wave runs defer-max
// online softmax over its half of the node's edge list; halves merge via LDS
// (flash-style partial combine), wave 0 of the pair writes the output.
template <int HC, int Hn, int LDc, bool ELU, typename OutT>
__global__ __launch_bounds__(512) void k_edge_fused(
    const __hip_bfloat16* __restrict__ xl, const __hip_bfloat16* __restrict__ xr,
    const int* __restrict__ rp, const int* __restrict__ srcs,
    const float* __restrict__ att, const float* __restrict__ bias,
    int N, OutT* __restrict__ out) {
  const int CPL = HC / 64;
  using VecT = typename VecSel<CPL>::T;
  __shared__ float lds_acc[4][HC];
  __shared__ float lds_m[4][64];
  __shared__ float lds_s[4][64];
  int lane = threadIdx.x & 63;
  int wv = threadIdx.x >> 6;
  int slot = wv >> 1, half = wv & 1;
  int n = blockIdx.x * 4 + slot;
  bool active = n < N;

  float a[CPL], xrv[CPL];
  float m = -INFINITY, sum = 0.f;
  float acc[CPL] = {};

  if (active) {
#pragma unroll
    for (int c = 0; c < CPL; c++) a[c] = att[lane * CPL + c];
    if constexpr (CPL == 8) {
      short8 v = *(const short8*)(xr + (size_t)n * LDc + lane * 8);
#pragma unroll
      for (int c = 0; c < 8; c++) xrv[c] = bf2f((unsigned short)v[c]);
    } else {
      unsigned int v = *(const unsigned int*)(xr + (size_t)n * LDc + lane * 2);
      xrv[0] = bf2f((unsigned short)(v & 0xffff));
      xrv[1] = bf2f((unsigned short)(v >> 16));
    }
    int s0 = rp[n], s1 = rp[n + 1];
    int mid = s0 + ((s1 - s0 + 1) >> 1);
    int lo = half ? mid : s0;
    int hi = half ? s1 : mid;

    auto loadrow = [&](int s) -> VecT {
      return *(const VecT*)(xl + (size_t)s * LDc + lane * CPL);
    };
    auto proc = [&](VecT v) {
      float xv[CPL];
      if constexpr (CPL == 8) {
#pragma unroll
        for (int c = 0; c < 8; c++) xv[c] = bf2f((unsigned short)v[c]);
      } else {
        xv[0] = bf2f((unsigned short)(v & 0xffff));
        xv[1] = bf2f((unsigned short)(v >> 16));
      }
      float p = 0.f;
#pragma unroll
      for (int c = 0; c < CPL; c++) {
        float t2 = xv[c] + xrv[c];
        t2 = t2 > 0.f ? t2 : 0.2f * t2;
        p = fmaf(t2, a[c], p);
      }
      const int RO = (Hn == 4) ? 8 : 32;
#pragma unroll
      for (int off = 1; off <= RO; off <<= 1) p += __shfl_xor(p, off, 64);
      if (__any(p > m + 8.f)) {  // rare rescale
        float mn = fmaxf(m, p);
        float corr = __expf(m - mn);
        float wgt = __expf(p - mn);
        sum = sum * corr + wgt;
#pragma unroll
        for (int c = 0; c < CPL; c++) acc[c] = fmaf(acc[c], corr, wgt * xv[c]);
        m = mn;
      } else {  // fast path
        float wgt = __expf(p - m);
        sum += wgt;
#pragma unroll
        for (int c = 0; c < CPL; c++) acc[c] = fmaf(wgt, xv[c], acc[c]);
      }
    };

    if (lo < hi) {
      VecT b0, b1;
      b0 = loadrow(srcs[lo]);
      if (lo + 1 < hi) b1 = loadrow(srcs[lo + 1]);
      int i = lo;
      for (; i + 1 < hi; i += 2) {
        VecT n0v, n1v;
        bool pf = (i + 2 < hi);
        if (pf) {
          int j0 = srcs[i + 2];
          int j1 = (i + 3 < hi) ? srcs[i + 3] : j0;
          n0v = loadrow(j0);
          n1v = loadrow(j1);
        }
        proc(b0);
        proc(b1);
        if (pf) { b0 = n0v; b1 = n1v; }
      }
      if (i < hi) proc(b0);
    }
  }

  if (half) {
    lds_m[slot][lane] = m;
    lds_s[slot][lane] = sum;
#pragma unroll
    for (int c = 0; c < CPL; c++) lds_acc[slot][lane * CPL + c] = acc[c];
  }
  __syncthreads();
  if (!half && active) {
    float mB = lds_m[slot][lane];
    float sB = lds_s[slot][lane];
    float M = fmaxf(m, mB);
    float cA = __expf(m - M);   // m finite: lower half always has >=1 edge (self-loop)
    float cB = __expf(mB - M);  // mB may be -inf -> cB = 0
    float s = sum * cA + sB * cB;
    float inv = 1.f / (s + 1e-16f);
#pragma unroll
    for (int c = 0; c < CPL; c++) {
      float r = (acc[c] * cA + lds_acc[slot][lane * CPL + c] * cB) * inv + bias[lane * CPL + c];
      if (ELU) r = r > 0.f ? r : expm1f(r);
      acc[c] = r;
    }
    if constexpr (sizeof(OutT) == 2) {
      short8 o;
#pragma unroll
      for (int c = 0; c < CPL; c++) {
        __hip_bfloat16 bv = __float2bfloat16(acc[c]);
        o[c] = __builtin_bit_cast(short, bv);
      }
      *(short8*)((__hip_bfloat16*)out + (size_t)n * HC + lane * CPL) = o;
    } else {
      f32x2 o; o.x = acc[0]; o.y = acc[1];
      *(f32x2*)((float*)out + (size_t)n * HC + lane * 2) = o;
    }
  }
}

extern "C" void kernel_launch(void* const* d_in, const int* in_sizes, int n_in,
                              void* d_out, int out_size, void* d_ws, size_t ws_size,
                              hipStream_t stream) {
  const int IN = 77, Kp1 = 96, Hh = 4, Cc = 128, HC = Hh * Cc;  // 512
  const int N = in_sizes[0] / IN;
  const int E = in_sizes[1] / 2;
  const int ET = E + N;

  const float* x   = (const float*)d_in[0];
  const int*   ei  = (const int*)d_in[1];
  const float* Wl1 = (const float*)d_in[2];  const float* bl1 = (const float*)d_in[3];
  const float* Wr1 = (const float*)d_in[4];  const float* br1 = (const float*)d_in[5];
  const float* att1= (const float*)d_in[6];  const float* b1  = (const float*)d_in[7];
  const float* Wl2 = (const float*)d_in[8];  const float* bl2 = (const float*)d_in[9];
  const float* Wr2 = (const float*)d_in[10]; const float* br2 = (const float*)d_in[11];
  const float* att2= (const float*)d_in[12]; const float* b2  = (const float*)d_in[13];
  const float* Wl3 = (const float*)d_in[14]; const float* bl3 = (const float*)d_in[15];
  const float* Wr3 = (const float*)d_in[16]; const float* br3 = (const float*)d_in[17];
  const float* att3= (const float*)d_in[18]; const float* b3  = (const float*)d_in[19];
  float* out = (float*)d_out;

  char* w = (char*)d_ws;
  size_t off = 0;
  auto alloc = [&](size_t bytes) -> void* {
    void* p = w + off;
    off += (bytes + 255) & ~(size_t)255;
    return p;
  };
  __hip_bfloat16* xlr = (__hip_bfloat16*)alloc((size_t)N * 2 * HC * 2);
  __hip_bfloat16* hb  = (__hip_bfloat16*)alloc((size_t)N * HC * 2);
  __hip_bfloat16* Wc1 = (__hip_bfloat16*)alloc((size_t)2 * HC * Kp1 * 2);
  __hip_bfloat16* Wc2 = (__hip_bfloat16*)alloc((size_t)2 * HC * HC * 2);
  __hip_bfloat16* Wc3 = (__hip_bfloat16*)alloc((size_t)2 * Cc * HC * 2);
  int*   deg    = (int*)alloc((size_t)N * 4);
  int*   rp     = (int*)alloc((size_t)(N + 1) * 4);
  int*   cursor = (int*)alloc((size_t)N * 4);
  int*   srcs   = (int*)alloc((size_t)ET * 4);

  // ---- fused casts ----
  CastArgs CA;
  int cum = 0;
  auto seg = [&](int idx, const float* src, __hip_bfloat16* dst, int rows, int K, int Kp, int row0) {
    CA.s[idx] = {src, dst, rows, K, Kp, row0, cum};
    cum += rows * Kp;
  };
  seg(0, Wl1, Wc1, HC, IN, Kp1, 0);
  seg(1, Wr1, Wc1, HC, IN, Kp1, HC);
  seg(2, Wl2, Wc2, HC, HC, HC, 0);
  seg(3, Wr2, Wc2, HC, HC, HC, HC);
  seg(4, Wl3, Wc3, Cc, HC, HC, 0);
  seg(5, Wr3, Wc3, Cc, HC, HC, Cc);
  seg(6, x,   hb,  N,  IN, Kp1, 0);
  CA.total = cum;
  k_cast_all<<<1024, 256, 0, stream>>>(CA);

  // ---- CSR build (by dst) ----
  hipMemsetAsync(deg, 0, (size_t)N * 4, stream);
  int tb = 256;
  k_hist<<<(ET + tb - 1) / tb, tb, 0, stream>>>(ei, E, N, deg);
  k_scan_one<<<1, 256, 0, stream>>>(deg, N, rp, cursor);
  k_scatter<<<(ET + tb - 1) / tb, tb, 0, stream>>>(ei, E, N, cursor, srcs);

  int nodeBlocks = (N + 3) / 4;  // 4 nodes/block, 2 waves per node
  int mb = (N + 127) / 128;

  // ---- layer 1 ----
  {
    dim3 g(2 * HC / 128, mb);
    gemm_mfma<<<g, 256, 0, stream>>>(hb, Wc1, bl1, br1, HC, xlr, N, Kp1, 2 * HC);
    k_edge_fused<512, 4, 1024, true, __hip_bfloat16><<<nodeBlocks, 512, 0, stream>>>(
        xlr, xlr + HC, rp, srcs, att1, b1, N, hb);
  }
  // ---- layer 2 ----
  {
    dim3 g(2 * HC / 128, mb);
    gemm_mfma<<<g, 256, 0, stream>>>(hb, Wc2, bl2, br2, HC, xlr, N, HC, 2 * HC);
    k_edge_fused<512, 4, 1024, true, __hip_bfloat16><<<nodeBlocks, 512, 0, stream>>>(
        xlr, xlr + HC, rp, srcs, att2, b2, N, hb);
  }
  // ---- layer 3 (1 head, 128 ch, fp32 out, no ELU) ----
  {
    dim3 g(2 * Cc / 128, mb);
    gemm_mfma<<<g, 256, 0, stream>>>(hb, Wc3, bl3, br3, Cc, xlr, N, HC, 2 * Cc);
    k_edge_fused<128, 1, 256, false, float><<<nodeBlocks, 512, 0, stream>>>(
        xlr, xlr + Cc, rp, srcs, att3, b3, N, out);
  }
}